// Round 9
// baseline (325.916 us; speedup 1.0000x reference)
//
#include <hip/hip_runtime.h>

// CTC batch cost (Keras ctc_batch_cost, full lengths).
// B=64, T=2048, C=128 (blank=127), L=256, S=513.
//
// Round-9: replace global_load_lds (LDS-DMA) staging with THROUGH-VGPR
// staging (global_load_dwordx4 -> regs -> ds_write_b128). Theory: LLVM's
// waitcnt pass cannot disambiguate which outstanding LDS-DMA wrote which
// ring slot, so every ds_read gather after an issue_chunk got a
// conservative s_waitcnt vmcnt(0) -- draining the just-issued chunk
// (~900cy) every iteration. That drain explains R7/R8's ~190cy/step stall
// and why both the instruction-count cut (R7) and the gather lookahead
// (R8) were neutral. With ds_write staging, gathers are ordered by
// precisely-tracked lgkmcnt only (same-wave DS ops; no barrier needed),
// and vmcnt gates only the ds_write group whose source regs were loaded a
// full iteration (~3600cy) earlier -> no stall.
//
// Numerics unchanged from R7/R8 (absmax 0.0 twice): per-lane block-float
// linear domain, exponent-only renorm every 4 steps, DPP neighbor pass,
// skip gates folded into fmaf. Zero transcendentals in the loop.

#define B_ 64
#define T_ 2048
#define C_ 128
#define L_ 256
#define BLANK_ (C_ - 1)
#define EPSF 1e-7f
#define LN2F 0.69314718055994530942f
#define CH_ 16                // rows per chunk
#define NCH_ (T_ / CH_)       // 128 chunks
#define SENT_ (-(1 << 28))    // "lane is all-zero" exponent sentinel

// lane l -> value of lane l-1; lane 0 -> 0. DPP ctrl 0x138 = wave_shr:1.
__device__ __forceinline__ float dpp_shr1_f(float x) {
    return __int_as_float(
        __builtin_amdgcn_update_dpp(0, __float_as_int(x), 0x138, 0xf, 0xf, false));
}
__device__ __forceinline__ int dpp_shr1_i(int x) {
    return __builtin_amdgcn_update_dpp(0, x, 0x138, 0xf, 0xf, false);
}

struct G { float pb, p1, p3, p5, p7; };

__launch_bounds__(64, 1)
__global__ void ctc_loss_kernel(const int* __restrict__ y_true,
                                const float* __restrict__ y_pred,
                                float* __restrict__ out) {
    const int b = blockIdx.x;
    const int l = threadIdx.x;  // 0..63

    __shared__ float ring[4][CH_ * C_];  // 4 x 16 rows x 128 f32 = 32 KB

    const int* __restrict__ lab = y_true + b * L_;
    const int4 lv = *(const int4*)(lab + 4 * l);   // labels 4l..4l+3
    const int e1 = lv.x, e3 = lv.y, e5 = lv.z, e7 = lv.w;
    const int em1 = (l > 0) ? lab[4 * l - 1] : -1;
    const float m1f = ((l > 0) && (e1 != em1)) ? 1.0f : 0.0f;  // skip gates
    const float m3f = (e3 != e1) ? 1.0f : 0.0f;
    const float m5f = (e5 != e3) ? 1.0f : 0.0f;
    const float m7f = (e7 != e5) ? 1.0f : 0.0f;
    const float m8f = (l == 63) ? 1.0f : 0.0f;     // state 512 inflow gate

    const float* __restrict__ base = y_pred + (size_t)b * (T_ * C_);

    // Through-VGPR staging: one chunk = 16 rows x 128 f32; per lane
    // 8 x float4 at element offset 4l + 256*i (coalesced dwordx4).
    float4 stg[8];
    auto load_chunk = [&](int t0) {
        const float* g = base + (size_t)t0 * C_ + 4 * l;
#pragma unroll
        for (int i = 0; i < 8; ++i)
            stg[i] = *(const float4*)(g + i * 256);
    };
    auto write_chunk = [&](float* __restrict__ buf) {
        float* p = buf + 4 * l;
#pragma unroll
        for (int i = 0; i < 8; ++i)
            *(float4*)(p + i * 256) = stg[i];
    };

    // eps pre-added at gather time (off the alpha chain)
    auto gather = [&](const float* __restrict__ row) -> G {
        G g;
        g.pb = row[BLANK_] + EPSF;
        g.p1 = row[e1] + EPSF;
        g.p3 = row[e3] + EPSF;
        g.p5 = row[e5] + EPSF;
        g.p7 = row[e7] + EPSF;
        return g;
    };

    // linear mantissas at lane-local scale 2^E
    float a0 = 0.f, a1 = 0.f, a2 = 0.f, a3 = 0.f, a4 = 0.f,
          a5 = 0.f, a6 = 0.f, a7 = 0.f, a8 = 0.f;
    int E = SENT_;
    float upscale = 1.0f;  // 2^(E_nbr - E), fixed within a 4-step window
    G g0, g1;              // gathers for the next two steps (rotated)

    auto step = [&](const G& g) {
        const float up = dpp_shr1_f(a7) * upscale;  // state 8l-1, rescaled
        const float n0 = (a0 + up) * g.pb;
        const float n1 = fmaf(m1f, up, a0 + a1) * g.p1;
        const float n2 = (a1 + a2) * g.pb;
        const float n3 = fmaf(m3f, a1, a2 + a3) * g.p3;
        const float n4 = (a3 + a4) * g.pb;
        const float n5 = fmaf(m5f, a3, a4 + a5) * g.p5;
        const float n6 = (a5 + a6) * g.pb;
        const float n7 = fmaf(m7f, a5, a6 + a7) * g.p7;
        const float n8 = fmaf(m8f, a7, a8) * g.pb;  // state 512
        a0 = n0; a1 = n1; a2 = n2; a3 = n3; a4 = n4;
        a5 = n5; a6 = n6; a7 = n7; a8 = n8;
    };

    // Window boundary: exponent-only renorm (exact: a_i*2^E invariant) +
    // E exchange (DPP) + precompute next window's neighbor upscale.
    auto boundary = [&]() {
        float mx = fmaxf(fmaxf(fmaxf(a0, a1), fmaxf(a2, a3)),
                         fmaxf(fmaxf(a4, a5), fmaxf(a6, a7)));
        mx = fmaxf(mx, a8);
        const bool z = (mx == 0.0f);
        const int e = (int)(__float_as_uint(mx) >> 23) - 127;
        const float s = z ? 1.0f : __uint_as_float((unsigned)(127 - e) << 23);
        a0 *= s; a1 *= s; a2 *= s; a3 *= s; a4 *= s;
        a5 *= s; a6 *= s; a7 *= s; a8 *= s;
        E = z ? SENT_ : (E + e);
        int upE = dpp_shr1_i(E);
        if (l == 0) upE = SENT_;
        if (E == SENT_) E = upE;            // adopt neighbor scale (exact)
        int d = upE - E;                    // 0 right after adoption
        d = min(max(d, -126), 120);
        upscale = __uint_as_float((unsigned)(d + 127) << 23);
    };

    // 16 steps with 2-step gather lookahead into the next chunk's buffer.
    auto run_chunk = [&](const float* __restrict__ cb,
                         const float* __restrict__ nb,
                         int jstart, bool last) {
#pragma unroll
        for (int j = 0; j < CH_; ++j) {
            if (j < 1 && jstart == 1) continue;  // folds at compile time
            G g2{};
            if (j + 2 < CH_)      g2 = gather(cb + (j + 2) * C_);
            else if (!last)       g2 = gather(nb + (j + 2 - CH_) * C_);
            step(g0);
            if ((j & 3) == 3) boundary();
            g0 = g1; g1 = g2;
        }
    };

    // ---- prologue: chunks 0,1,2 into LDS; chunk 3 held in regs ----
    load_chunk(0);        write_chunk(ring[0]);
    load_chunk(CH_);      write_chunk(ring[1]);
    load_chunk(2 * CH_);  write_chunk(ring[2]);
    load_chunk(3 * CH_);  // stays in stg until end of iter k=0

    // ---- chunk 0: t=0 init + steps t=1..15 ----
    if (l == 0) { a0 = ring[0][BLANK_] + EPSF; a1 = ring[0][e1] + EPSF; E = 0; }
    boundary();                       // seeds lane1's adoption of E
    g0 = gather(&ring[0][1 * C_]);
    g1 = gather(&ring[0][2 * C_]);
    run_chunk(ring[0], ring[1], 1, false);
    write_chunk(ring[3]);             // chunk 3 (regs loaded ~1 iter ago)
    load_chunk(4 * CH_);              // chunk 4 -> regs

    // ---- chunks 1..126: run k; write chunk k+3; load chunk k+4 ----
    for (int k = 1; k <= 126; ++k) {
        run_chunk(ring[k & 3], ring[(k + 1) & 3], 0, false);
        if (k + 3 < NCH_) write_chunk(ring[(k + 3) & 3]);
        if (k + 4 < NCH_) load_chunk((k + 4) * CH_);
    }

    // ---- chunk 127 ----
    run_chunk(ring[127 & 3], (const float*)nullptr, 0, true);

    if (l == 63) {
        // loss = -ln((a511 + a512) * 2^E)  (boundary at t=2047 normalized)
        out[b] = -(__logf(a7 + a8) + (float)E * LN2F);
    }
}

extern "C" void kernel_launch(void* const* d_in, const int* in_sizes, int n_in,
                              void* d_out, int out_size, void* d_ws, size_t ws_size,
                              hipStream_t stream) {
    const int* y_true = (const int*)d_in[0];
    const float* y_pred = (const float*)d_in[1];
    float* out = (float*)d_out;
    ctc_loss_kernel<<<B_, 64, 0, stream>>>(y_true, y_pred, out);
}

// Round 11
// 291.588 us; speedup vs baseline: 1.1177x; 1.1177x over previous
//
#include <hip/hip_runtime.h>

// CTC batch cost (Keras ctc_batch_cost, full lengths).
// B=64, T=2048, C=128 (blank=127), L=256, S=513.
//
// Round-11 = Round-8 numerics/staging with two compiler-legible fixes for
// the ~190cy/step memory stall (R7/R8 both ~226cy/step):
//  (1) FOUR DISTINCT __shared__ arrays (bufA..bufD) + chunk loop unrolled x4
//      so every LDS-DMA destination and every ds_read source is a distinct
//      named object at compile time. LLVM's waitcnt pass conservatively
//      inserts vmcnt waits before ds_reads that may alias outstanding
//      LDS-DMA writes; a dynamically-indexed ring (ring[k&3]) may-aliases
//      everything -> ~900cy drain per chunk. Distinct objects -> NoAlias.
//  (2) 3-step gather lookahead pinned with __builtin_amdgcn_sched_barrier(0)
//      between the lookahead ds_reads and the step compute, so the machine
//      scheduler cannot sink the gathers back to their uses (R8's manual
//      g0/g1/g2 rotation was neutral because it could). 3 steps ~ 300cy
//      >= ds_read latency (~120cy).
// Numerics unchanged (absmax 0.0 in R7/R8): per-lane block-float linear
// domain, exponent-only renorm every 4 steps, DPP wave_shr:1 neighbor pass,
// skip gates folded into fmaf. Zero transcendentals in the loop.

#define B_ 64
#define T_ 2048
#define C_ 128
#define L_ 256
#define BLANK_ (C_ - 1)
#define EPSF 1e-7f
#define LN2F 0.69314718055994530942f
#define CH_ 16                // rows per chunk
#define NCH_ (T_ / CH_)       // 128 chunks
#define SENT_ (-(1 << 28))    // "lane is all-zero" exponent sentinel

typedef __attribute__((address_space(1))) const void glob_cv;
typedef __attribute__((address_space(3))) void lds_v;

// One global_load_lds_dwordx4: 64 lanes x 16B = 1024B (two rows).
__device__ __forceinline__ void gl2lds16(const float* g, float* l) {
    __builtin_amdgcn_global_load_lds((glob_cv*)g, (lds_v*)l, 16, 0, 0);
}

#define WAIT_VM(n) asm volatile("s_waitcnt vmcnt(" #n ")" ::: "memory")

// lane l -> value of lane l-1; lane 0 -> 0. DPP ctrl 0x138 = wave_shr:1.
__device__ __forceinline__ float dpp_shr1_f(float x) {
    return __int_as_float(
        __builtin_amdgcn_update_dpp(0, __float_as_int(x), 0x138, 0xf, 0xf, false));
}
__device__ __forceinline__ int dpp_shr1_i(int x) {
    return __builtin_amdgcn_update_dpp(0, x, 0x138, 0xf, 0xf, false);
}

struct G { float pb, p1, p3, p5, p7; };

__launch_bounds__(64, 1)
__global__ void ctc_loss_kernel(const int* __restrict__ y_true,
                                const float* __restrict__ y_pred,
                                float* __restrict__ out) {
    const int b = blockIdx.x;
    const int l = threadIdx.x;  // 0..63

    // Four distinct LDS chunk buffers (8 KB each, 32 KB total).
    __shared__ float bufA[CH_ * C_], bufB[CH_ * C_],
                     bufC[CH_ * C_], bufD[CH_ * C_];

    const int* __restrict__ lab = y_true + b * L_;
    const int4 lv = *(const int4*)(lab + 4 * l);   // labels 4l..4l+3
    const int e1 = lv.x, e3 = lv.y, e5 = lv.z, e7 = lv.w;
    const int em1 = (l > 0) ? lab[4 * l - 1] : -1;
    const float m1f = ((l > 0) && (e1 != em1)) ? 1.0f : 0.0f;  // skip gates
    const float m3f = (e3 != e1) ? 1.0f : 0.0f;
    const float m5f = (e5 != e3) ? 1.0f : 0.0f;
    const float m7f = (e7 != e5) ? 1.0f : 0.0f;
    const float m8f = (l == 63) ? 1.0f : 0.0f;     // state 512 inflow gate

    const float* __restrict__ base = y_pred + (size_t)b * (T_ * C_);

    auto issue_chunk = [&](int t0, float* __restrict__ buf) {
        const float* g = base + (size_t)t0 * C_ + 4 * l;  // lane*16B
#pragma unroll
        for (int i = 0; i < 8; ++i)
            gl2lds16(g + i * 256, buf + i * 256);
    };

    // eps pre-added at gather time (off the alpha chain)
    auto gather = [&](const float* __restrict__ row) -> G {
        G g;
        g.pb = row[BLANK_] + EPSF;
        g.p1 = row[e1] + EPSF;
        g.p3 = row[e3] + EPSF;
        g.p5 = row[e5] + EPSF;
        g.p7 = row[e7] + EPSF;
        return g;
    };

    // linear mantissas at lane-local scale 2^E
    float a0 = 0.f, a1 = 0.f, a2 = 0.f, a3 = 0.f, a4 = 0.f,
          a5 = 0.f, a6 = 0.f, a7 = 0.f, a8 = 0.f;
    int E = SENT_;
    float upscale = 1.0f;  // 2^(E_nbr - E), fixed within a 4-step window
    G g0, g1, g2;          // gathers for the next three steps (rotated)

    auto step = [&](const G& g) {
        const float up = dpp_shr1_f(a7) * upscale;  // state 8l-1, rescaled
        const float n0 = (a0 + up) * g.pb;
        const float n1 = fmaf(m1f, up, a0 + a1) * g.p1;
        const float n2 = (a1 + a2) * g.pb;
        const float n3 = fmaf(m3f, a1, a2 + a3) * g.p3;
        const float n4 = (a3 + a4) * g.pb;
        const float n5 = fmaf(m5f, a3, a4 + a5) * g.p5;
        const float n6 = (a5 + a6) * g.pb;
        const float n7 = fmaf(m7f, a5, a6 + a7) * g.p7;
        const float n8 = fmaf(m8f, a7, a8) * g.pb;  // state 512
        a0 = n0; a1 = n1; a2 = n2; a3 = n3; a4 = n4;
        a5 = n5; a6 = n6; a7 = n7; a8 = n8;
    };

    // Window boundary: exponent-only renorm (exact: a_i*2^E invariant) +
    // E exchange (DPP) + precompute next window's neighbor upscale.
    auto boundary = [&]() {
        float mx = fmaxf(fmaxf(fmaxf(a0, a1), fmaxf(a2, a3)),
                         fmaxf(fmaxf(a4, a5), fmaxf(a6, a7)));
        mx = fmaxf(mx, a8);
        const bool z = (mx == 0.0f);
        const int e = (int)(__float_as_uint(mx) >> 23) - 127;
        const float s = z ? 1.0f : __uint_as_float((unsigned)(127 - e) << 23);
        a0 *= s; a1 *= s; a2 *= s; a3 *= s; a4 *= s;
        a5 *= s; a6 *= s; a7 *= s; a8 *= s;
        E = z ? SENT_ : (E + e);
        int upE = dpp_shr1_i(E);
        if (l == 0) upE = SENT_;
        if (E == SENT_) E = upE;            // adopt neighbor scale (exact)
        int d = upE - E;
        d = min(max(d, -126), 120);
        upscale = __uint_as_float((unsigned)(d + 127) << 23);
    };

    // 16 steps; step j consumes row j via g0 (gathered 3 steps earlier).
    // Lookahead gathers pinned before the compute by sched_barrier(0).
    auto run_chunk = [&](const float* __restrict__ cb,
                         const float* __restrict__ nb,
                         int jstart, bool last) {
#pragma unroll
        for (int j = 0; j < CH_; ++j) {
            if (j < 1 && jstart == 1) continue;  // folds at compile time
            G g3{};
            if (j + 3 < CH_)      g3 = gather(cb + (j + 3) * C_);
            else if (!last)       g3 = gather(nb + (j + 3 - CH_) * C_);
            __builtin_amdgcn_sched_barrier(0);   // gathers stay 3 steps early
            step(g0);
            if ((j & 3) == 3) boundary();
            g0 = g1; g1 = g2; g2 = g3;
        }
    };

    // ---- prologue: chunks 0,1,2 in flight ----
    issue_chunk(0, bufA);
    issue_chunk(CH_, bufB);
    issue_chunk(2 * CH_, bufC);

    // ---- group 0 (chunks 0..3), chunk 0 carries the t=0 init ----
    WAIT_VM(8);                        // chunks 0,1 landed; 2 in flight
    issue_chunk(3 * CH_, bufD);
    if (l == 0) { a0 = bufA[BLANK_] + EPSF; a1 = bufA[e1] + EPSF; E = 0; }
    boundary();                        // seeds lane1's adoption of E
    g0 = gather(bufA + 1 * C_);
    g1 = gather(bufA + 2 * C_);
    g2 = gather(bufA + 3 * C_);
    run_chunk(bufA, bufB, 1, false);
    WAIT_VM(8); issue_chunk(4 * CH_, bufA); run_chunk(bufB, bufC, 0, false);
    WAIT_VM(8); issue_chunk(5 * CH_, bufB); run_chunk(bufC, bufD, 0, false);
    WAIT_VM(8); issue_chunk(6 * CH_, bufC); run_chunk(bufD, bufA, 0, false);

    // ---- groups 1..30 (chunks 4..123); at chunk c issue chunk c+3 ----
    for (int m = 1; m <= 30; ++m) {
        const int c = 4 * m;
        WAIT_VM(8); issue_chunk((c + 3) * CH_, bufD); run_chunk(bufA, bufB, 0, false);
        WAIT_VM(8); issue_chunk((c + 4) * CH_, bufA); run_chunk(bufB, bufC, 0, false);
        WAIT_VM(8); issue_chunk((c + 5) * CH_, bufB); run_chunk(bufC, bufD, 0, false);
        WAIT_VM(8); issue_chunk((c + 6) * CH_, bufC); run_chunk(bufD, bufA, 0, false);
    }

    // ---- group 31 (chunks 124..127) ----
    WAIT_VM(8); issue_chunk(127 * CH_, bufD); run_chunk(bufA, bufB, 0, false);
    WAIT_VM(8);                        // 126 landed; 127 in flight
    run_chunk(bufB, bufC, 0, false);
    WAIT_VM(0);                        // 127 landed (issued 2 chunks ago)
    run_chunk(bufC, bufD, 0, false);
    run_chunk(bufD, (const float*)nullptr, 0, true);

    if (l == 63) {
        // boundary at t=2047 normalized: loss = -ln((a511 + a512) * 2^E)
        out[b] = -(__logf(a7 + a8) + (float)E * LN2F);
    }
}

extern "C" void kernel_launch(void* const* d_in, const int* in_sizes, int n_in,
                              void* d_out, int out_size, void* d_ws, size_t ws_size,
                              hipStream_t stream) {
    const int* y_true = (const int*)d_in[0];
    const float* y_pred = (const float*)d_in[1];
    float* out = (float*)d_out;
    ctc_loss_kernel<<<B_, 64, 0, stream>>>(y_true, y_pred, out);
}

// Round 12
// 254.692 us; speedup vs baseline: 1.2796x; 1.1449x over previous
//
#include <hip/hip_runtime.h>

// CTC batch cost (Keras ctc_batch_cost, full lengths).
// B=64, T=2048, C=128 (blank=127), L=256, S=513.
//
// Round-12: ISSUE-SLOT DIET. Re-fit of R7-R11 counters shows the single
// busy SIMD is ~69% issue-occupied (VALUBusy 4.3% x4 active-CU x4 SIMD):
// we are issue-bound (~78 slots/step in R8), not stall-bound. Cuts:
//  (1) G g[4] + lookahead 4 (16%4==0 -> identical phase every chunk, slot
//      index j&3 is compile-time) -> the ~15 rotation v_movs/step vanish.
//  (2) 5 column base pointers precomputed once; every gather is
//      ds_read vaddr offset:imm (buf*8KB + row*512B < 64KB imm) -> the ~10
//      per-step address-VALU ops vanish.
//  (3) no sched_barrier (R11: order-pinning regressed, cf. m141).
// Unchanged (absmax 0.0 in R7/R8/R11): LDS-DMA staging + WAIT_VM(8)
// never-drain discipline, per-lane block-float linear numerics, exponent
// renorm every 4 steps (frontier <=2 states/step x4 < 8 states/lane keeps
// exponent adoption exact), DPP wave_shr:1 neighbor pass.

#define B_ 64
#define T_ 2048
#define C_ 128
#define L_ 256
#define BLANK_ (C_ - 1)
#define EPSF 1e-7f
#define LN2F 0.69314718055994530942f
#define CH_ 16                // rows per chunk
#define NCH_ (T_ / CH_)       // 128 chunks
#define SENT_ (-(1 << 28))    // "lane is all-zero" exponent sentinel

typedef __attribute__((address_space(1))) const void glob_cv;
typedef __attribute__((address_space(3))) void lds_v;

__device__ __forceinline__ void gl2lds16(const float* g, float* l) {
    __builtin_amdgcn_global_load_lds((glob_cv*)g, (lds_v*)l, 16, 0, 0);
}

#define WAIT_VM(n) asm volatile("s_waitcnt vmcnt(" #n ")" ::: "memory")

// lane l -> value of lane l-1; lane 0 -> 0. DPP ctrl 0x138 = wave_shr:1.
__device__ __forceinline__ float dpp_shr1_f(float x) {
    return __int_as_float(
        __builtin_amdgcn_update_dpp(0, __float_as_int(x), 0x138, 0xf, 0xf, false));
}
__device__ __forceinline__ int dpp_shr1_i(int x) {
    return __builtin_amdgcn_update_dpp(0, x, 0x138, 0xf, 0xf, false);
}

struct G { float pb, p1, p3, p5, p7; };

__launch_bounds__(64, 1)
__global__ void ctc_loss_kernel(const int* __restrict__ y_true,
                                const float* __restrict__ y_pred,
                                float* __restrict__ out) {
    const int b = blockIdx.x;
    const int l = threadIdx.x;  // 0..63

    __shared__ float ring[4][CH_ * C_];  // 4 bufs x 16 rows x 128 f32 = 32 KB

    const int* __restrict__ lab = y_true + b * L_;
    const int4 lv = *(const int4*)(lab + 4 * l);   // labels 4l..4l+3
    const int e1 = lv.x, e3 = lv.y, e5 = lv.z, e7 = lv.w;
    const int em1 = (l > 0) ? lab[4 * l - 1] : -1;
    const float m1f = ((l > 0) && (e1 != em1)) ? 1.0f : 0.0f;  // skip gates
    const float m3f = (e3 != e1) ? 1.0f : 0.0f;
    const float m5f = (e5 != e3) ? 1.0f : 0.0f;
    const float m7f = (e7 != e5) ? 1.0f : 0.0f;
    const float m8f = (l == 63) ? 1.0f : 0.0f;     // state 512 inflow gate

    const float* __restrict__ base = y_pred + (size_t)b * (T_ * C_);

    // Column base pointers into LDS: all gathers become vaddr + imm offset.
    const float* __restrict__ rb = &ring[0][0];
    const float* __restrict__ cB = rb + BLANK_;
    const float* __restrict__ c1 = rb + e1;
    const float* __restrict__ c3 = rb + e3;
    const float* __restrict__ c5 = rb + e5;
    const float* __restrict__ c7 = rb + e7;

    auto issue_chunk = [&](int t0, int buf) {
        const float* g = base + (size_t)t0 * C_ + 4 * l;  // lane*16B
#pragma unroll
        for (int i = 0; i < 8; ++i)
            gl2lds16(g + i * 256, &ring[buf][i * 256]);
    };

    G g[4];  // lookahead-4 slots; slot index always compile-time (j&3)
    auto fill = [&](int slot, int off) {  // off = buf*2048 + row*128 (const)
        g[slot].pb = cB[off] + EPSF;
        g[slot].p1 = c1[off] + EPSF;
        g[slot].p3 = c3[off] + EPSF;
        g[slot].p5 = c5[off] + EPSF;
        g[slot].p7 = c7[off] + EPSF;
    };

    // linear mantissas at lane-local scale 2^E
    float a0 = 0.f, a1 = 0.f, a2 = 0.f, a3 = 0.f, a4 = 0.f,
          a5 = 0.f, a6 = 0.f, a7 = 0.f, a8 = 0.f;
    int E = SENT_;
    float upscale = 1.0f;  // 2^(E_nbr - E), fixed within a 4-step window

    auto step = [&](const G& q) {
        const float up = dpp_shr1_f(a7) * upscale;  // state 8l-1, rescaled
        const float n0 = (a0 + up) * q.pb;
        const float n1 = fmaf(m1f, up, a0 + a1) * q.p1;
        const float n2 = (a1 + a2) * q.pb;
        const float n3 = fmaf(m3f, a1, a2 + a3) * q.p3;
        const float n4 = (a3 + a4) * q.pb;
        const float n5 = fmaf(m5f, a3, a4 + a5) * q.p5;
        const float n6 = (a5 + a6) * q.pb;
        const float n7 = fmaf(m7f, a5, a6 + a7) * q.p7;
        const float n8 = fmaf(m8f, a7, a8) * q.pb;  // state 512
        a0 = n0; a1 = n1; a2 = n2; a3 = n3; a4 = n4;
        a5 = n5; a6 = n6; a7 = n7; a8 = n8;
    };

    auto boundary = [&]() {
        float mx = fmaxf(fmaxf(fmaxf(a0, a1), fmaxf(a2, a3)),
                         fmaxf(fmaxf(a4, a5), fmaxf(a6, a7)));
        mx = fmaxf(mx, a8);
        const bool z = (mx == 0.0f);
        const int e = (int)(__float_as_uint(mx) >> 23) - 127;
        const float s = z ? 1.0f : __uint_as_float((unsigned)(127 - e) << 23);
        a0 *= s; a1 *= s; a2 *= s; a3 *= s; a4 *= s;
        a5 *= s; a6 *= s; a7 *= s; a8 *= s;
        E = z ? SENT_ : (E + e);
        int upE = dpp_shr1_i(E);
        if (l == 0) upE = SENT_;
        if (E == SENT_) E = upE;            // adopt neighbor scale (exact)
        int d = upE - E;
        d = min(max(d, -126), 120);
        upscale = __uint_as_float((unsigned)(d + 127) << 23);
    };

    // Chunk body: step j consumes slot j&3 (row j), then refills the slot
    // with row j+4 (crossing into buf bn for j>=12). Invariant g[t&3]=row t.
    auto run_chunk = [&](int bc, int bn, int jstart, bool last) {
#pragma unroll
        for (int j = 0; j < CH_; ++j) {
            if (j == 0 && jstart) continue;      // folds at compile time
            step(g[j & 3]);
            if (!last || j < 12) {
                const int off = (j < 12) ? (bc * 2048 + (j + 4) * 128)
                                         : (bn * 2048 + (j - 12) * 128);
                fill(j & 3, off);
            }
            if ((j & 3) == 3) boundary();
        }
    };

    // ---- prologue: chunks 0,1,2 in flight ----
    issue_chunk(0, 0);
    issue_chunk(CH_, 1);
    issue_chunk(2 * CH_, 2);

    // ---- chunk 0 (buf0): t=0 init + steps t=1..15 ----
    WAIT_VM(8);                        // chunks 0,1 landed; 2 in flight
    issue_chunk(3 * CH_, 3);
    if (l == 0) { a0 = ring[0][BLANK_] + EPSF; a1 = ring[0][e1] + EPSF; E = 0; }
    boundary();                        // seeds lane1's adoption of E
    fill(1, 1 * 128);                  // rows 1..4 for slots 1,2,3,0
    fill(2, 2 * 128);
    fill(3, 3 * 128);
    fill(0, 4 * 128);
    run_chunk(0, 1, 1, false);
    WAIT_VM(8); issue_chunk(4 * CH_, 0); run_chunk(1, 2, 0, false);
    WAIT_VM(8); issue_chunk(5 * CH_, 1); run_chunk(2, 3, 0, false);
    WAIT_VM(8); issue_chunk(6 * CH_, 2); run_chunk(3, 0, 0, false);

    // ---- groups 1..30 (chunks 4..123); at chunk c issue chunk c+3 ----
    for (int m = 1; m <= 30; ++m) {
        const int c = 4 * m;
        WAIT_VM(8); issue_chunk((c + 3) * CH_, 3); run_chunk(0, 1, 0, false);
        WAIT_VM(8); issue_chunk((c + 4) * CH_, 0); run_chunk(1, 2, 0, false);
        WAIT_VM(8); issue_chunk((c + 5) * CH_, 1); run_chunk(2, 3, 0, false);
        WAIT_VM(8); issue_chunk((c + 6) * CH_, 2); run_chunk(3, 0, 0, false);
    }

    // ---- chunks 124..127 ----
    WAIT_VM(8); issue_chunk(127 * CH_, 3); run_chunk(0, 1, 0, false);
    WAIT_VM(8);                        // 126 landed; 127 in flight
    run_chunk(1, 2, 0, false);
    WAIT_VM(0);                        // 127 landed
    run_chunk(2, 3, 0, false);
    run_chunk(3, 3, 0, true);

    if (l == 63) {
        // boundary at t=2047 normalized: loss = -ln((a511 + a512) * 2^E)
        out[b] = -(__logf(a7 + a8) + (float)E * LN2F);
    }
}

extern "C" void kernel_launch(void* const* d_in, const int* in_sizes, int n_in,
                              void* d_out, int out_size, void* d_ws, size_t ws_size,
                              hipStream_t stream) {
    const int* y_true = (const int*)d_in[0];
    const float* y_pred = (const float*)d_in[1];
    float* out = (float*)d_out;
    ctc_loss_kernel<<<B_, 64, 0, stream>>>(y_true, y_pred, out);
}